// Round 6
// baseline (459.746 us; speedup 1.0000x reference)
//
#include <hip/hip_runtime.h>
#include <hip/hip_bf16.h>
#include <cstdint>
#include <cstddef>

using bf16    = __bf16;
using bf16x8  = __attribute__((ext_vector_type(8))) __bf16;
using floatx4 = __attribute__((ext_vector_type(4))) float;

// Swizzled ("packet") layout for all bf16 GEMM operands:
//   packet = 1024B = one (16-row x 32-k) block of a row-major [R x K] matrix
//   packet index  = (row>>4) * (K>>5) + (k>>5)
//   lane l (16B) holds row = 16*(row>>4) + (l&15), k-chunk l>>4 (8 elems)
// => element (row,k) at  packet*512 + (((k>>3)&3)*16 + (row&15))*8 + (k&7)
// A packet is exactly one MFMA fragment-set for a wave: fragment load =
// one global_load_dwordx4 per lane, 1KB contiguous per wave.

__device__ __forceinline__ void async_cp16(const bf16* g, bf16* l) {
    __builtin_amdgcn_global_load_lds(
        (__attribute__((address_space(1))) void*)const_cast<bf16*>(g),
        (__attribute__((address_space(3))) void*)l,
        16, 0, 0);
}

// ---------------------------------------------------------------------------
// prep+cvt fused: yb < prepRows -> token-mix rows of xv/xr;
//                 else          -> fp32->bf16 convert of one weight row-block.
// All outputs swizzled.
// ---------------------------------------------------------------------------
__global__ __launch_bounds__(256) void prep_cvt(
    const float* __restrict__ x, const float* __restrict__ tmv,
    const float* __restrict__ tmr, const float* __restrict__ xxp,
    const float* __restrict__ w0, const float* __restrict__ w1,
    const float* __restrict__ w2, bf16* __restrict__ xv, bf16* __restrict__ xr,
    bf16* __restrict__ o0, bf16* __restrict__ o1, bf16* __restrict__ o2,
    int C, int prepRows) {
    const int t = threadIdx.x;
    const int p = t >> 6, l = t & 63;
    const int c0 = blockIdx.x << 7;
    const int k = c0 + (p << 5) + ((l >> 4) << 3);
    const int yb = blockIdx.y;
    const int C4 = C >> 4;

    if (yb < prepRows) {
        const int r0 = yb << 4;
        const int row = r0 + (l & 15);
        const float4* xi = (const float4*)&x[(size_t)row * C + k];
        float4 a0 = xi[0], a1 = xi[1];
        float4 mv0 = *(const float4*)&tmv[k], mv1 = *(const float4*)&tmv[k + 4];
        float4 mr0 = *(const float4*)&tmr[k], mr1 = *(const float4*)&tmr[k + 4];
        float4 x00 = *(const float4*)&xxp[k], x01 = *(const float4*)&xxp[k + 4];
        float xa[8]  = {a0.x, a0.y, a0.z, a0.w, a1.x, a1.y, a1.z, a1.w};
        float mva[8] = {mv0.x, mv0.y, mv0.z, mv0.w, mv1.x, mv1.y, mv1.z, mv1.w};
        float mra[8] = {mr0.x, mr0.y, mr0.z, mr0.w, mr1.x, mr1.y, mr1.z, mr1.w};
        float x0a[8] = {x00.x, x00.y, x00.z, x00.w, x01.x, x01.y, x01.z, x01.w};
        bf16x8 ov, og;
#pragma unroll
        for (int u = 0; u < 8; ++u) {
            ov[u] = (bf16)(xa[u] * mva[u] + (1.0f - mva[u]) * x0a[u]);
            og[u] = (bf16)(xa[u] * mra[u] + (1.0f - mra[u]) * x0a[u]);
        }
        const size_t off = ((size_t)(r0 >> 4) * (C >> 5) + (c0 >> 5) + p) * 512 + l * 8;
        *(bf16x8*)&xv[off] = ov;
        *(bf16x8*)&xr[off] = og;
    } else {
        int z = yb - prepRows;
        const float* wsrc;
        bf16* wdst;
        if (z < C4) {
            wsrc = w0; wdst = o0;
        } else if (z < 2 * C4) {
            wsrc = w1; wdst = o1; z -= C4;
        } else {
            wsrc = w2; wdst = o2; z -= 2 * C4;
        }
        const int r0 = z << 4;
        const int row = r0 + (l & 15);
        const float4* wi = (const float4*)&wsrc[(size_t)row * C + k];
        float4 a0 = wi[0], a1 = wi[1];
        float wa[8] = {a0.x, a0.y, a0.z, a0.w, a1.x, a1.y, a1.z, a1.w};
        bf16x8 ov;
#pragma unroll
        for (int u = 0; u < 8; ++u) ov[u] = (bf16)wa[u];
        const size_t off = ((size_t)(r0 >> 4) * (C >> 5) + (c0 >> 5) + p) * 512 + l * 8;
        *(bf16x8*)&wdst[off] = ov;
    }
}

// ---------------------------------------------------------------------------
// Direct-stream GEMM (no LDS, no barriers): C = A @ Bw^T on swizzled operands.
// 128x128 tile, 4 waves (2x2 of 64x64). Each wave loads its own fragments
// straight from global (1KB contiguous per wave per fragment); ping-pong
// depth-1 register prefetch lets the compiler emit partial vmcnt waits —
// the fine-grained pipelining the LDS+barrier structure could not express.
// Cross-wave packet duplication (2x) is absorbed by L1.
// EPI: 0 = store bf16 swizzled; 1 = store bf16(sigmoid(acc)*Vaux) swizzled;
//      2 = store fp32 row-major.
// ---------------------------------------------------------------------------
template <int EPI>
__global__ __launch_bounds__(256, 2) void gemm_ds(
    const bf16* __restrict__ A, const bf16* __restrict__ Bw,
    const bf16* __restrict__ Vaux, bf16* __restrict__ Ob,
    float* __restrict__ Of, int M, int N, int K) {
    const int bid = blockIdx.x;
    const int Mt  = M >> 7;           // m-tiles
    int mt, nt;
    if ((Mt & 7) == 0) {              // XCD-aware swizzle: XCD owns an m-band
        const int xcd = bid & 7;
        const int tt  = bid >> 3;
        const int mpx = Mt >> 3;      // m-tiles per XCD
        mt = xcd * mpx + (tt % mpx);
        nt = tt / mpx;
    } else {
        mt = bid % Mt;
        nt = bid / Mt;
    }

    const int tid  = threadIdx.x;
    const int wave = tid >> 6;
    const int lane = tid & 63;
    const int quad = lane >> 4;
    const int l16  = lane & 15;
    const int m0   = mt * 128;
    const int n0   = nt * 128;
    const int wm   = (wave >> 1) * 64;
    const int wn   = (wave & 1) * 64;
    const int KS   = K >> 5;          // packets per row-block

    floatx4 acc[4][4];
#pragma unroll
    for (int i = 0; i < 4; ++i)
#pragma unroll
        for (int j = 0; j < 4; ++j) acc[i][j] = (floatx4){0.f, 0.f, 0.f, 0.f};

    // wave's fragment base pointers (row-blocks rbA..rbA+3 / rbB..rbB+3)
    const int rbA = (m0 >> 4) + (wave >> 1) * 4;
    const int rbB = (n0 >> 4) + (wave & 1) * 4;
    const bf16* pA = A + (size_t)rbA * KS * 512 + lane * 8;
    const bf16* pB = Bw + (size_t)rbB * KS * 512 + lane * 8;

    bf16x8 aP[4], bP[4], aQ[4], bQ[4];

#define LOAD_PK(ab, bb, pk)                                                   \
    {                                                                         \
        _Pragma("unroll") for (int i = 0; i < 4; ++i) {                       \
            ab[i] = *(const bf16x8*)(pA + ((size_t)i * KS + (pk)) * 512);     \
            bb[i] = *(const bf16x8*)(pB + ((size_t)i * KS + (pk)) * 512);     \
        }                                                                     \
    }
#define MFMA_PK(ab, bb)                                                       \
    {                                                                         \
        _Pragma("unroll") for (int i = 0; i < 4; ++i)                         \
            _Pragma("unroll") for (int j = 0; j < 4; ++j)                     \
                acc[i][j] = __builtin_amdgcn_mfma_f32_16x16x32_bf16(          \
                    ab[i], bb[j], acc[i][j], 0, 0, 0);                        \
    }

    LOAD_PK(aP, bP, 0);
#pragma unroll 1
    for (int pk = 0; pk + 2 < KS; pk += 2) {
        LOAD_PK(aQ, bQ, pk + 1);   // prefetch next packet while computing
        MFMA_PK(aP, bP);
        LOAD_PK(aP, bP, pk + 2);
        MFMA_PK(aQ, bQ);
    }
    LOAD_PK(aQ, bQ, KS - 1);
    MFMA_PK(aP, bP);
    MFMA_PK(aQ, bQ);
#undef LOAD_PK
#undef MFMA_PK

    // epilogue: C/D layout (16x16x32): col = lane&15, row = quad*4 + reg
    const int rbase = quad * 4;
#pragma unroll
    for (int i = 0; i < 4; ++i) {
        const int rbg = ((m0 + wm) >> 4) + i;
#pragma unroll
        for (int j = 0; j < 4; ++j) {
            const int col = n0 + wn + j * 16 + l16;
            if (EPI == 2) {
#pragma unroll
                for (int r = 0; r < 4; ++r) {
                    const int row = m0 + wm + i * 16 + rbase + r;
                    Of[(size_t)row * N + col] = acc[i][j][r];
                }
            } else {
                const size_t base = ((size_t)rbg * (N >> 5) + (col >> 5)) * 512 +
                                    (size_t)(((col >> 3) & 3) << 4) * 8 + (col & 7);
#pragma unroll
                for (int r = 0; r < 4; ++r) {
                    const size_t o = base + (size_t)(rbase + r) * 8;
                    const float va = acc[i][j][r];
                    if (EPI == 0) {
                        Ob[o] = (bf16)va;
                    } else {
                        const float vv = (float)Vaux[o];
                        const float sg = 1.0f / (1.0f + __expf(-va));
                        Ob[o] = (bf16)(sg * vv);
                    }
                }
            }
        }
    }
}

// ---------------------------------------------------------------------------
// fallback path (small ws): BK=32 LDS pipeline with vbuf in d_out
// ---------------------------------------------------------------------------
template <int EPI>
__global__ __launch_bounds__(256) void gemm_swz(
    const bf16* __restrict__ A, const bf16* __restrict__ Bw,
    const bf16* __restrict__ Vaux, bf16* __restrict__ Ob,
    float* __restrict__ Of, int M, int N, int K) {
    __shared__ __align__(16) bf16 sA[128 * 32];
    __shared__ __align__(16) bf16 sB[128 * 32];

    const int tid  = threadIdx.x;
    const int wave = tid >> 6;
    const int lane = tid & 63;
    const int quad = lane >> 4;
    const int l16  = lane & 15;
    const int m0   = blockIdx.y * 128;
    const int n0   = blockIdx.x * 128;
    const int wm   = (wave >> 1) * 64;
    const int wn   = (wave & 1) * 64;
    const int kslabs = K >> 5;

    floatx4 acc[4][4];
#pragma unroll
    for (int i = 0; i < 4; ++i)
#pragma unroll
        for (int j = 0; j < 4; ++j) acc[i][j] = (floatx4){0.f, 0.f, 0.f, 0.f};

    const bf16* gA0 = A + ((size_t)((m0 >> 4) + wave) * kslabs) * 512 + lane * 8;
    const bf16* gA1 = gA0 + (size_t)4 * kslabs * 512;
    const bf16* gB0 = Bw + ((size_t)((n0 >> 4) + wave) * kslabs) * 512 + lane * 8;
    const bf16* gB1 = gB0 + (size_t)4 * kslabs * 512;
    bf16* lA0 = &sA[wave * 512];
    bf16* lA1 = &sA[2048 + wave * 512];
    bf16* lB0 = &sB[wave * 512];
    bf16* lB1 = &sB[2048 + wave * 512];

    for (int it = 0; it < kslabs; ++it) {
        __syncthreads();
        async_cp16(gA0, lA0);
        async_cp16(gA1, lA1);
        async_cp16(gB0, lB0);
        async_cp16(gB1, lB1);
        gA0 += 512; gA1 += 512; gB0 += 512; gB1 += 512;
        __syncthreads();

        bf16x8 af[4], bfg[4];
#pragma unroll
        for (int i = 0; i < 4; ++i)
            af[i] = *(const bf16x8*)&sA[(((wm >> 4) + i) << 9) + (lane << 3)];
#pragma unroll
        for (int j = 0; j < 4; ++j)
            bfg[j] = *(const bf16x8*)&sB[(((wn >> 4) + j) << 9) + (lane << 3)];
#pragma unroll
        for (int i = 0; i < 4; ++i)
#pragma unroll
            for (int j = 0; j < 4; ++j)
                acc[i][j] = __builtin_amdgcn_mfma_f32_16x16x32_bf16(
                    af[i], bfg[j], acc[i][j], 0, 0, 0);
    }

    const int rbase = quad * 4;
#pragma unroll
    for (int i = 0; i < 4; ++i) {
        const int rb = ((m0 + wm) >> 4) + i;
#pragma unroll
        for (int j = 0; j < 4; ++j) {
            const int col = n0 + wn + j * 16 + l16;
            if (EPI == 2) {
#pragma unroll
                for (int r = 0; r < 4; ++r) {
                    const int row = m0 + wm + i * 16 + rbase + r;
                    Of[(size_t)row * N + col] = acc[i][j][r];
                }
            } else {
                const size_t base = ((size_t)rb * (N >> 5) + (col >> 5)) * 512 +
                                    (size_t)(((col >> 3) & 3) << 4) * 8 + (col & 7);
#pragma unroll
                for (int r = 0; r < 4; ++r) {
                    const size_t o = base + (size_t)(rbase + r) * 8;
                    const float va = acc[i][j][r];
                    if (EPI == 0) {
                        Ob[o] = (bf16)va;
                    } else {
                        const float vv = (float)Vaux[o];
                        const float sg = 1.0f / (1.0f + __expf(-va));
                        Ob[o] = (bf16)(sg * vv);
                    }
                }
            }
        }
    }
}

extern "C" void kernel_launch(void* const* d_in, const int* in_sizes, int n_in,
                              void* d_out, int out_size, void* d_ws, size_t ws_size,
                              hipStream_t stream) {
    // inputs: 0:x 1:time_first 2:tmk 3:tmv 4:tmr 5:xx 6:aa 7:bb 8:pp
    //         9:w_key 10:w_value 11:w_rec 12:w_out
    const int C = in_sizes[1];              // 2048
    const int M = in_sizes[0] / C;          // B*T = 8192
    const size_t MC = (size_t)M * C;
    const size_t CC = (size_t)C * C;

    const float* x   = (const float*)d_in[0];
    const float* tmv = (const float*)d_in[3];
    const float* tmr = (const float*)d_in[4];
    const float* xxp = (const float*)d_in[5];
    const float* wv  = (const float*)d_in[10];
    const float* wr  = (const float*)d_in[11];
    const float* wo  = (const float*)d_in[12];
    float* out = (float*)d_out;

    uint8_t* ws = (uint8_t*)d_ws;
    const size_t need_full = MC * 6 + CC * 6;
    const int prepRows = M / 16;
    dim3 gridP(C / 128, M / 16 + 3 * (C / 16));
    const int nBlk = (M / 128) * (C / 128);

    if (ws_size >= need_full) {
        bf16* xv   = (bf16*)(ws);
        bf16* xr   = (bf16*)(ws + MC * 2);
        bf16* rwkv = (bf16*)(ws + MC * 4);
        bf16* wvb  = (bf16*)(ws + MC * 6);
        bf16* wrb  = (bf16*)(ws + MC * 6 + CC * 2);
        bf16* wob  = (bf16*)(ws + MC * 6 + CC * 4);
        // v (bf16, MC*2 bytes) parks in d_out (fp32, MC*4 bytes): fully
        // consumed by gemm_ds<1> before gemm_ds<2> overwrites d_out.
        bf16* vbuf = (bf16*)d_out;

        prep_cvt<<<gridP, 256, 0, stream>>>(x, tmv, tmr, xxp, wv, wr, wo,
                                            xv, xr, wvb, wrb, wob, C, prepRows);
        // v = xv @ Wv^T                   (wkv == v, see analysis)
        gemm_ds<0><<<nBlk, 256, 0, stream>>>(xv, wvb, nullptr, vbuf, nullptr, M, C, C);
        // rwkv = sigmoid(xr @ Wr^T) * v
        gemm_ds<1><<<nBlk, 256, 0, stream>>>(xr, wrb, vbuf, rwkv, nullptr, M, C, C);
        // out = rwkv @ Wo^T
        gemm_ds<2><<<nBlk, 256, 0, stream>>>(rwkv, wob, nullptr, nullptr, out, M, C, C);
    } else {
        bf16* xv   = (bf16*)(ws);
        bf16* xr   = (bf16*)(ws + MC * 2);
        bf16* vbuf = (bf16*)d_out;
        bf16* wvb  = (bf16*)(ws + MC * 4);
        bf16* wrb  = (bf16*)(ws + MC * 4 + CC * 2);
        bf16* wob  = (bf16*)(ws + MC * 4 + CC * 4);
        bf16* rwkv = xv;  // xv dead after GEMM_v

        dim3 gridG(C / 128, M / 128);
        prep_cvt<<<gridP, 256, 0, stream>>>(x, tmv, tmr, xxp, wv, wr, wo,
                                            xv, xr, wvb, wrb, wob, C, prepRows);
        gemm_swz<0><<<gridG, 256, 0, stream>>>(xv, wvb, nullptr, vbuf, nullptr, M, C, C);
        gemm_swz<1><<<gridG, 256, 0, stream>>>(xr, wrb, vbuf, rwkv, nullptr, M, C, C);
        gemm_swz<2><<<gridG, 256, 0, stream>>>(rwkv, wob, nullptr, nullptr, out, M, C, C);
    }
}

// Round 7
// 394.822 us; speedup vs baseline: 1.1644x; 1.1644x over previous
//
#include <hip/hip_runtime.h>
#include <hip/hip_bf16.h>
#include <cstdint>
#include <cstddef>

using bf16     = __bf16;
using bf16x8   = __attribute__((ext_vector_type(8))) __bf16;
using floatx16 = __attribute__((ext_vector_type(16))) float;

// P32 packet layout for all bf16 GEMM operands (matched to 32x32x16 MFMA):
//   packet = 1024B = one (32-row x 16-k) block of a row-major [R x K] matrix
//   packet index = (row>>5)*(K>>4) + (k>>4)
//   lane l (16B) holds row = 32*(row>>5) + (l&31), k-chunk (l>>5)*8 (8 elems)
// => element (row,k) at packet*512 + (((k>>3)&1)*32 + (row&31))*8 + (k&7)
// One packet = one wave A/B fragment for v_mfma_f32_32x32x16_bf16:
//   A[m = lane&31][k = (lane>>5)*8 + j]  (generalizes the verified 16x16 map)
// C/D layout (m74/m101): col = lane&31, row = (reg&3) + 8*(reg>>2) + 4*(lane>>5)

__device__ __forceinline__ void async_cp16(const bf16* g, bf16* l) {
    __builtin_amdgcn_global_load_lds(
        (__attribute__((address_space(1))) void*)const_cast<bf16*>(g),
        (__attribute__((address_space(3))) void*)l,
        16, 0, 0);
}

// ---------------------------------------------------------------------------
// prep+cvt fused (P32 outputs): yb < prepRows -> token-mix 32 rows of xv/xr;
// else -> fp32->bf16 convert of one 32-row block of a weight.
// Block covers 32 rows x 64 cols; thread t: kp p=t>>6, lane l=t&63.
// ---------------------------------------------------------------------------
__global__ __launch_bounds__(256) void prep_cvt(
    const float* __restrict__ x, const float* __restrict__ tmv,
    const float* __restrict__ tmr, const float* __restrict__ xxp,
    const float* __restrict__ w0, const float* __restrict__ w1,
    const float* __restrict__ w2, bf16* __restrict__ xv, bf16* __restrict__ xr,
    bf16* __restrict__ o0, bf16* __restrict__ o1, bf16* __restrict__ o2,
    int C, int prepRows) {
    const int t = threadIdx.x;
    const int p = t >> 6, l = t & 63;
    const int c0 = blockIdx.x << 6;
    const int k = c0 + (p << 4) + ((l >> 5) << 3);
    const int yb = blockIdx.y;
    const int C5 = C >> 5;
    const int KP = C >> 4;

    if (yb < prepRows) {
        const int r0 = yb << 5;
        const int row = r0 + (l & 31);
        const float4* xi = (const float4*)&x[(size_t)row * C + k];
        float4 a0 = xi[0], a1 = xi[1];
        float4 mv0 = *(const float4*)&tmv[k], mv1 = *(const float4*)&tmv[k + 4];
        float4 mr0 = *(const float4*)&tmr[k], mr1 = *(const float4*)&tmr[k + 4];
        float4 x00 = *(const float4*)&xxp[k], x01 = *(const float4*)&xxp[k + 4];
        float xa[8]  = {a0.x, a0.y, a0.z, a0.w, a1.x, a1.y, a1.z, a1.w};
        float mva[8] = {mv0.x, mv0.y, mv0.z, mv0.w, mv1.x, mv1.y, mv1.z, mv1.w};
        float mra[8] = {mr0.x, mr0.y, mr0.z, mr0.w, mr1.x, mr1.y, mr1.z, mr1.w};
        float x0a[8] = {x00.x, x00.y, x00.z, x00.w, x01.x, x01.y, x01.z, x01.w};
        bf16x8 ov, og;
#pragma unroll
        for (int u = 0; u < 8; ++u) {
            ov[u] = (bf16)(xa[u] * mva[u] + (1.0f - mva[u]) * x0a[u]);
            og[u] = (bf16)(xa[u] * mra[u] + (1.0f - mra[u]) * x0a[u]);
        }
        const size_t off = ((size_t)(r0 >> 5) * KP + (c0 >> 4) + p) * 512 + l * 8;
        *(bf16x8*)&xv[off] = ov;
        *(bf16x8*)&xr[off] = og;
    } else {
        int z = yb - prepRows;
        const float* wsrc;
        bf16* wdst;
        if (z < C5) {
            wsrc = w0; wdst = o0;
        } else if (z < 2 * C5) {
            wsrc = w1; wdst = o1; z -= C5;
        } else {
            wsrc = w2; wdst = o2; z -= 2 * C5;
        }
        const int r0 = z << 5;
        const int row = r0 + (l & 31);
        const float4* wi = (const float4*)&wsrc[(size_t)row * C + k];
        float4 a0 = wi[0], a1 = wi[1];
        float wa[8] = {a0.x, a0.y, a0.z, a0.w, a1.x, a1.y, a1.z, a1.w};
        bf16x8 ov;
#pragma unroll
        for (int u = 0; u < 8; ++u) ov[u] = (bf16)wa[u];
        const size_t off = ((size_t)(r0 >> 5) * KP + (c0 >> 4) + p) * 512 + l * 8;
        *(bf16x8*)&wdst[off] = ov;
    }
}

// ---------------------------------------------------------------------------
// FUSED v/r GEMM, 32x32x16 MFMA, BK=64, 128x128 tile, XCD-swizzled 1D grid.
// Per iter: 16 async_cp16 (4KB contiguous per wave per tensor), then per wave
// 32 ds_read_b128 + 32 MFMA (2x the FLOP/instr of 16x16).
// ---------------------------------------------------------------------------
__global__ __launch_bounds__(256, 2) void gemm_vr(
    const bf16* __restrict__ XV, const bf16* __restrict__ XR,
    const bf16* __restrict__ WV, const bf16* __restrict__ WR,
    bf16* __restrict__ RW, int M, int N, int K) {
    __shared__ __align__(16) bf16 sXV[8192];
    __shared__ __align__(16) bf16 sXR[8192];
    __shared__ __align__(16) bf16 sWV[8192];
    __shared__ __align__(16) bf16 sWR[8192];

    const int bid = blockIdx.x;
    const int Mt  = M >> 7;
    int mt, nt;
    if ((Mt & 7) == 0) {
        const int xcd = bid & 7;
        const int tt  = bid >> 3;
        const int mpx = Mt >> 3;
        mt = xcd * mpx + (tt % mpx);
        nt = tt / mpx;
    } else {
        mt = bid % Mt;
        nt = bid / Mt;
    }

    const int tid  = threadIdx.x;
    const int wave = tid >> 6;
    const int lane = tid & 63;
    const int m0   = mt * 128;
    const int n0   = nt * 128;
    const int wm   = (wave >> 1) * 64;
    const int wn   = (wave & 1) * 64;
    const int KP   = K >> 4;   // 16-k packets per row-block

    floatx16 accv[2][2], accr[2][2];
#pragma unroll
    for (int i = 0; i < 2; ++i)
#pragma unroll
        for (int j = 0; j < 2; ++j) {
#pragma unroll
            for (int u = 0; u < 16; ++u) { accv[i][j][u] = 0.f; accr[i][j][u] = 0.f; }
        }

    // wave w stages row-block w (4 packets = 4KB contiguous) of each tensor
    const bf16* gXV = XV + ((size_t)((m0 >> 5) + wave) * KP) * 512 + lane * 8;
    const bf16* gXR = XR + ((size_t)((m0 >> 5) + wave) * KP) * 512 + lane * 8;
    const bf16* gWV = WV + ((size_t)((n0 >> 5) + wave) * KP) * 512 + lane * 8;
    const bf16* gWR = WR + ((size_t)((n0 >> 5) + wave) * KP) * 512 + lane * 8;
    const int dW = wave * 4 * 512;
    const int rba = (wave >> 1) * 2;
    const int rbb = (wave & 1) * 2;

    const int iters = K >> 6;
    for (int it = 0; it < iters; ++it) {
        __syncthreads();
#pragma unroll
        for (int q = 0; q < 4; ++q) {
            async_cp16(gXV + q * 512, &sXV[dW + q * 512]);
            async_cp16(gXR + q * 512, &sXR[dW + q * 512]);
            async_cp16(gWV + q * 512, &sWV[dW + q * 512]);
            async_cp16(gWR + q * 512, &sWR[dW + q * 512]);
        }
        gXV += 2048; gXR += 2048; gWV += 2048; gWR += 2048;
        __syncthreads();

#pragma unroll
        for (int ks = 0; ks < 4; ++ks) {
            bf16x8 aV[2], bV[2], aR[2], bR[2];
#pragma unroll
            for (int i = 0; i < 2; ++i) {
                aV[i] = *(const bf16x8*)&sXV[((rba + i) * 4 + ks) * 512 + (lane << 3)];
                aR[i] = *(const bf16x8*)&sXR[((rba + i) * 4 + ks) * 512 + (lane << 3)];
            }
#pragma unroll
            for (int j = 0; j < 2; ++j) {
                bV[j] = *(const bf16x8*)&sWV[((rbb + j) * 4 + ks) * 512 + (lane << 3)];
                bR[j] = *(const bf16x8*)&sWR[((rbb + j) * 4 + ks) * 512 + (lane << 3)];
            }
#pragma unroll
            for (int i = 0; i < 2; ++i)
#pragma unroll
                for (int j = 0; j < 2; ++j) {
                    accv[i][j] = __builtin_amdgcn_mfma_f32_32x32x16_bf16(
                        aV[i], bV[j], accv[i][j], 0, 0, 0);
                    accr[i][j] = __builtin_amdgcn_mfma_f32_32x32x16_bf16(
                        aR[i], bR[j], accr[i][j], 0, 0, 0);
                }
        }
    }

    // epilogue: rwkv = bf16(sigmoid(accr)*accv), stored in P32 layout.
    // C/D: col = lane&31, row = (r&3) + 8*(r>>2) + 4*(lane>>5)
    const int l5 = (lane >> 5) * 4;
    const int KPn = N >> 4;
#pragma unroll
    for (int i = 0; i < 2; ++i) {
        const int rbg = ((m0 + wm) >> 5) + i;
#pragma unroll
        for (int j = 0; j < 2; ++j) {
            const int col = n0 + wn + j * 32 + (lane & 31);
            const size_t base = ((size_t)rbg * KPn + (col >> 4)) * 512 +
                                (size_t)(((col >> 3) & 1) * 256) + (col & 7);
#pragma unroll
            for (int r = 0; r < 16; ++r) {
                const int rr = (r & 3) + 8 * (r >> 2) + l5;
                const float sg = 1.0f / (1.0f + __expf(-accr[i][j][r]));
                RW[base + (size_t)rr * 8] = (bf16)(sg * accv[i][j][r]);
            }
        }
    }
}

// ---------------------------------------------------------------------------
// out-GEMM, 32x32x16 MFMA, BK=64, 128x256 tile. Of = A @ Bw^T, fp32 row-major.
// LDS: sA 16KB + sB 32KB.
// ---------------------------------------------------------------------------
__global__ __launch_bounds__(256, 2) void gemm_o(
    const bf16* __restrict__ A, const bf16* __restrict__ Bw,
    float* __restrict__ Of, int M, int N, int K) {
    __shared__ __align__(16) bf16 sA[8192];
    __shared__ __align__(16) bf16 sB[16384];

    const int bid = blockIdx.x;
    const int Mt  = M >> 7;
    int mt, nt;
    if ((Mt & 7) == 0) {
        const int xcd = bid & 7;
        const int tt  = bid >> 3;
        const int mpx = Mt >> 3;
        mt = xcd * mpx + (tt % mpx);
        nt = tt / mpx;
    } else {
        mt = bid % Mt;
        nt = bid / Mt;
    }

    const int tid  = threadIdx.x;
    const int wave = tid >> 6;
    const int lane = tid & 63;
    const int m0   = mt * 128;
    const int n0   = nt * 256;
    const int wm   = (wave >> 1) * 64;
    const int wnb  = (wave & 1) * 128;
    const int KP   = K >> 4;

    floatx16 acc[2][4];
#pragma unroll
    for (int i = 0; i < 2; ++i)
#pragma unroll
        for (int j = 0; j < 4; ++j)
#pragma unroll
            for (int u = 0; u < 16; ++u) acc[i][j][u] = 0.f;

    const bf16* gA  = A + ((size_t)((m0 >> 5) + wave) * KP) * 512 + lane * 8;
    const bf16* gB0 = Bw + ((size_t)((n0 >> 5) + wave) * KP) * 512 + lane * 8;
    const bf16* gB1 = gB0 + (size_t)4 * KP * 512;
    const int dA = wave * 4 * 512;
    const int dB0 = wave * 4 * 512;
    const int dB1 = (wave + 4) * 4 * 512;
    const int rba = (wave >> 1) * 2;
    const int rbb = (wave & 1) * 4;

    const int iters = K >> 6;
    for (int it = 0; it < iters; ++it) {
        __syncthreads();
#pragma unroll
        for (int q = 0; q < 4; ++q) {
            async_cp16(gA + q * 512, &sA[dA + q * 512]);
            async_cp16(gB0 + q * 512, &sB[dB0 + q * 512]);
            async_cp16(gB1 + q * 512, &sB[dB1 + q * 512]);
        }
        gA += 2048; gB0 += 2048; gB1 += 2048;
        __syncthreads();

#pragma unroll
        for (int ks = 0; ks < 4; ++ks) {
            bf16x8 aF[2], bF[4];
#pragma unroll
            for (int i = 0; i < 2; ++i)
                aF[i] = *(const bf16x8*)&sA[((rba + i) * 4 + ks) * 512 + (lane << 3)];
#pragma unroll
            for (int j = 0; j < 4; ++j)
                bF[j] = *(const bf16x8*)&sB[((rbb + j) * 4 + ks) * 512 + (lane << 3)];
#pragma unroll
            for (int i = 0; i < 2; ++i)
#pragma unroll
                for (int j = 0; j < 4; ++j)
                    acc[i][j] = __builtin_amdgcn_mfma_f32_32x32x16_bf16(
                        aF[i], bF[j], acc[i][j], 0, 0, 0);
        }
    }

    const int l5 = (lane >> 5) * 4;
#pragma unroll
    for (int i = 0; i < 2; ++i) {
#pragma unroll
        for (int j = 0; j < 4; ++j) {
            const int col = n0 + wnb + j * 32 + (lane & 31);
#pragma unroll
            for (int r = 0; r < 16; ++r) {
                const int row = m0 + wm + i * 32 + (r & 3) + 8 * (r >> 2) + l5;
                Of[(size_t)row * N + col] = acc[i][j][r];
            }
        }
    }
}

// ---------------------------------------------------------------------------
// fallback (small ws): single-GEMM 128x128 P32 kernel, EPI 0/1/2 as before.
// ---------------------------------------------------------------------------
template <int EPI>
__global__ __launch_bounds__(256, 2) void gemm_one(
    const bf16* __restrict__ A, const bf16* __restrict__ Bw,
    const bf16* __restrict__ Vaux, bf16* __restrict__ Ob,
    float* __restrict__ Of, int M, int N, int K) {
    __shared__ __align__(16) bf16 sA[8192];
    __shared__ __align__(16) bf16 sB[8192];

    const int bid = blockIdx.x;
    const int Mt  = M >> 7;
    int mt, nt;
    if ((Mt & 7) == 0) {
        const int xcd = bid & 7;
        const int tt  = bid >> 3;
        const int mpx = Mt >> 3;
        mt = xcd * mpx + (tt % mpx);
        nt = tt / mpx;
    } else {
        mt = bid % Mt;
        nt = bid / Mt;
    }

    const int tid  = threadIdx.x;
    const int wave = tid >> 6;
    const int lane = tid & 63;
    const int m0   = mt * 128;
    const int n0   = nt * 128;
    const int wm   = (wave >> 1) * 64;
    const int wn   = (wave & 1) * 64;
    const int KP   = K >> 4;

    floatx16 acc[2][2];
#pragma unroll
    for (int i = 0; i < 2; ++i)
#pragma unroll
        for (int j = 0; j < 2; ++j)
#pragma unroll
            for (int u = 0; u < 16; ++u) acc[i][j][u] = 0.f;

    const bf16* gA = A + ((size_t)((m0 >> 5) + wave) * KP) * 512 + lane * 8;
    const bf16* gB = Bw + ((size_t)((n0 >> 5) + wave) * KP) * 512 + lane * 8;
    const int dW = wave * 4 * 512;
    const int rba = (wave >> 1) * 2;
    const int rbb = (wave & 1) * 2;

    const int iters = K >> 6;
    for (int it = 0; it < iters; ++it) {
        __syncthreads();
#pragma unroll
        for (int q = 0; q < 4; ++q) {
            async_cp16(gA + q * 512, &sA[dW + q * 512]);
            async_cp16(gB + q * 512, &sB[dW + q * 512]);
        }
        gA += 2048; gB += 2048;
        __syncthreads();

#pragma unroll
        for (int ks = 0; ks < 4; ++ks) {
            bf16x8 aF[2], bF[2];
#pragma unroll
            for (int i = 0; i < 2; ++i)
                aF[i] = *(const bf16x8*)&sA[((rba + i) * 4 + ks) * 512 + (lane << 3)];
#pragma unroll
            for (int j = 0; j < 2; ++j)
                bF[j] = *(const bf16x8*)&sB[((rbb + j) * 4 + ks) * 512 + (lane << 3)];
#pragma unroll
            for (int i = 0; i < 2; ++i)
#pragma unroll
                for (int j = 0; j < 2; ++j)
                    acc[i][j] = __builtin_amdgcn_mfma_f32_32x32x16_bf16(
                        aF[i], bF[j], acc[i][j], 0, 0, 0);
        }
    }

    const int l5 = (lane >> 5) * 4;
    const int KPn = N >> 4;
#pragma unroll
    for (int i = 0; i < 2; ++i) {
        const int rbg = ((m0 + wm) >> 5) + i;
#pragma unroll
        for (int j = 0; j < 2; ++j) {
            const int col = n0 + wn + j * 32 + (lane & 31);
            if (EPI == 2) {
#pragma unroll
                for (int r = 0; r < 16; ++r) {
                    const int row = m0 + wm + i * 32 + (r & 3) + 8 * (r >> 2) + l5;
                    Of[(size_t)row * N + col] = acc[i][j][r];
                }
            } else {
                const size_t base = ((size_t)rbg * KPn + (col >> 4)) * 512 +
                                    (size_t)(((col >> 3) & 1) * 256) + (col & 7);
#pragma unroll
                for (int r = 0; r < 16; ++r) {
                    const int rr = (r & 3) + 8 * (r >> 2) + l5;
                    const size_t o = base + (size_t)rr * 8;
                    const float va = acc[i][j][r];
                    if (EPI == 0) {
                        Ob[o] = (bf16)va;
                    } else {
                        const float vv = (float)Vaux[o];
                        const float sg = 1.0f / (1.0f + __expf(-va));
                        Ob[o] = (bf16)(sg * vv);
                    }
                }
            }
        }
    }
}

extern "C" void kernel_launch(void* const* d_in, const int* in_sizes, int n_in,
                              void* d_out, int out_size, void* d_ws, size_t ws_size,
                              hipStream_t stream) {
    // inputs: 0:x 1:time_first 2:tmk 3:tmv 4:tmr 5:xx 6:aa 7:bb 8:pp
    //         9:w_key 10:w_value 11:w_rec 12:w_out
    const int C = in_sizes[1];              // 2048
    const int M = in_sizes[0] / C;          // B*T = 8192
    const size_t MC = (size_t)M * C;
    const size_t CC = (size_t)C * C;

    const float* x   = (const float*)d_in[0];
    const float* tmv = (const float*)d_in[3];
    const float* tmr = (const float*)d_in[4];
    const float* xxp = (const float*)d_in[5];
    const float* wv  = (const float*)d_in[10];
    const float* wr  = (const float*)d_in[11];
    const float* wo  = (const float*)d_in[12];
    float* out = (float*)d_out;

    uint8_t* ws = (uint8_t*)d_ws;
    const size_t need_full = MC * 6 + CC * 6;
    const int prepRows = M / 32;
    dim3 gridP(C / 64, M / 32 + 3 * (C / 32));
    const int nBlkVR = (M / 128) * (C / 128);
    const int nBlkO  = (M / 128) * (C / 256);

    if (ws_size >= need_full) {
        bf16* xv   = (bf16*)(ws);
        bf16* xr   = (bf16*)(ws + MC * 2);
        bf16* rwkv = (bf16*)(ws + MC * 4);
        bf16* wvb  = (bf16*)(ws + MC * 6);
        bf16* wrb  = (bf16*)(ws + MC * 6 + CC * 2);
        bf16* wob  = (bf16*)(ws + MC * 6 + CC * 4);

        prep_cvt<<<gridP, 256, 0, stream>>>(x, tmv, tmr, xxp, wv, wr, wo,
                                            xv, xr, wvb, wrb, wob, C, prepRows);
        // rwkv = sigmoid(xr@Wr^T) * (xv@Wv^T)   (wkv == v, see analysis)
        gemm_vr<<<nBlkVR, 256, 0, stream>>>(xv, xr, wvb, wrb, rwkv, M, C, C);
        // out = rwkv @ Wo^T
        gemm_o<<<nBlkO, 256, 0, stream>>>(rwkv, wob, out, M, C, C);
    } else {
        // fallback: park v (bf16) in d_out (fp32 => 2x bytes); consumed by
        // gemm_one<1> before gemm_one<2> overwrites d_out.
        bf16* xv   = (bf16*)(ws);
        bf16* xr   = (bf16*)(ws + MC * 2);
        bf16* vbuf = (bf16*)d_out;
        bf16* wvb  = (bf16*)(ws + MC * 4);
        bf16* wrb  = (bf16*)(ws + MC * 4 + CC * 2);
        bf16* wob  = (bf16*)(ws + MC * 4 + CC * 4);
        bf16* rwkv = xv;  // xv dead after the v-GEMM

        prep_cvt<<<gridP, 256, 0, stream>>>(x, tmv, tmr, xxp, wv, wr, wo,
                                            xv, xr, wvb, wrb, wob, C, prepRows);
        gemm_one<0><<<nBlkVR, 256, 0, stream>>>(xv, wvb, nullptr, vbuf, nullptr, M, C, C);
        gemm_one<1><<<nBlkVR, 256, 0, stream>>>(xr, wrb, vbuf, rwkv, nullptr, M, C, C);
        gemm_one<2><<<nBlkVR, 256, 0, stream>>>(rwkv, wob, nullptr, nullptr, out, M, C, C);
    }
}